// Round 13
// baseline (492.606 us; speedup 1.0000x reference)
//
#include <hip/hip_runtime.h>
#include <hip/hip_bf16.h>
#include <cstddef>
#include <cstdint>

#define IN_DIM 512
#define R_DIM 128
#define F_DIM 64
#define H_NUM 4
#define OUT_DIM 64
#define HF 256  // H_NUM * F_DIM

typedef __attribute__((ext_vector_type(4))) float f32x4;
typedef __attribute__((ext_vector_type(8))) short bf16x8;

typedef const __attribute__((address_space(1))) void gas_void;
typedef __attribute__((address_space(3))) void las_void;

__device__ __forceinline__ float bf2f(ushort u) {
    union { uint i; float f; } v; v.i = ((uint)u) << 16; return v.f;
}
__device__ __forceinline__ ushort f2bf(float f) {
    union { float f; uint i; } v; v.f = f;
    uint r = v.i + 0x7fff + ((v.i >> 16) & 1);
    return (ushort)(r >> 16);
}
__device__ __forceinline__ float u2f(uint u) {
    union { uint i; float f; } v; v.i = u; return v.f;
}

// ---------------------------------------------------------------- zero ints
__global__ __launch_bounds__(256) void zero_i32(int* __restrict__ p, int n) {
    int i = blockIdx.x * 256 + threadIdx.x;
    if (i < n) p[i] = 0;
}

// --------------------------- fold W_seq @ W_lin, both layers in one launch
__global__ __launch_bounds__(256) void wcomb_kernel(const float* __restrict__ WlinH,
                                                    const float* __restrict__ WseqH,
                                                    const float* __restrict__ WlinC,
                                                    const float* __restrict__ WseqC,
                                                    ushort* __restrict__ Wc1,
                                                    ushort* __restrict__ Wc2) {
    int idx = blockIdx.x * 256 + threadIdx.x;
    if (idx < H_NUM * F_DIM * IN_DIM) {
        int i  = idx & (IN_DIM - 1);
        int hf = idx >> 9;          // h*64 + f
        int h  = hf >> 6;
        const float* ws = WseqH + (size_t)hf * R_DIM;
        const float* wl = WlinH + (size_t)h * R_DIM * IN_DIM + i;
        float acc = 0.0f;
#pragma unroll 8
        for (int r = 0; r < R_DIM; ++r) acc += ws[r] * wl[(size_t)r * IN_DIM];
        Wc1[idx] = f2bf(acc);
    } else {
        int idx2 = idx - H_NUM * F_DIM * IN_DIM;
        if (idx2 >= OUT_DIM * HF) return;
        int j = idx2 & (HF - 1);
        int o = idx2 >> 8;
        const float* ws = WseqC + (size_t)o * R_DIM;
        const float* wl = WlinC + j;
        float acc = 0.0f;
#pragma unroll 8
        for (int r = 0; r < R_DIM; ++r) acc += ws[r] * wl[(size_t)r * HF];
        Wc2[idx2] = f2bf(acc);
    }
}

// ----------------------------- bf16 MFMA GEMM TN, fp32 A converted in-flight
// BM=32, BN=128, BK=64, 256 threads. LDS 20KB -> 8 blocks/CU.
template<int BN, int K, int FS>
__global__ __launch_bounds__(256) void gemm_f32a(const float* __restrict__ A,
                                                 const ushort* __restrict__ B,
                                                 ushort* __restrict__ C,
                                                 int M, int Ntot,
                                                 const float* __restrict__ a1,
                                                 const float* __restrict__ b1,
                                                 const float* __restrict__ a2,
                                                 const float* __restrict__ b2,
                                                 float* __restrict__ f1o,
                                                 float* __restrict__ f2o) {
    constexpr int NF = 4;            // 4 col-blocks (one head) per wave
    __shared__ ushort As[32 * 64];
    __shared__ ushort Bs[BN * 64];
    const int tid = threadIdx.x;
    const int wave = tid >> 6;
    const int lane = tid & 63;
    const int lr = lane & 15;
    const int lg = lane >> 4;
    const int wr = wave & 1;         // row half
    const int wc = wave >> 1;        // col half (= head within block)

    const int b = blockIdx.x;
    const int by = (b >> 3) & 1;
    const int bx = (b >> 4) * 8 + (b & 7);
    const int nbx = (M + 31) >> 5;
    if (bx >= nbx) return;
    const int m0 = bx * 32;
    const int n0 = by * BN;
    const int h0 = by * 2;

    int base[2];
#pragma unroll
    for (int ks = 0; ks < 2; ++ks)
        base[ks] = lr * 128 + (((ks * 4 + lg) ^ (lr & 7)) * 16);
    const int abase0 = wr * 2048 + base[0];
    const int abase1 = wr * 2048 + base[1];

    const int s_row = tid >> 3;
    const int s_lchunk = tid & 7;
    int s_grow = m0 + s_row;
    if (s_grow >= M) s_grow = M - 1;
    const int s_ldsoff = s_row * 128 + ((s_lchunk ^ (s_row & 7)) * 16);
    const int s_goff = s_lchunk * 8;

    f32x4 acc[NF];
#pragma unroll
    for (int cb = 0; cb < NF; ++cb) acc[cb] = (f32x4)0.0f;

    for (int k0 = 0; k0 < K; k0 += 64) {
#pragma unroll
        for (int r = 0; r < BN / 32; ++r) {
            int off = r * 4096 + tid * 16;
            int row = off >> 7;
            int kch = ((off >> 4) & 7) ^ (row & 7);
            const ushort* g = B + (size_t)(n0 + row) * K + k0 + kch * 8;
            __builtin_amdgcn_global_load_lds((gas_void*)g,
                                             (las_void*)((char*)Bs + off), 16, 0, 0);
        }
        {
            const float* g = A + (size_t)s_grow * K + k0 + s_goff;
            float4 v0 = *(const float4*)(g);
            float4 v1 = *(const float4*)(g + 4);
            ushort us[8] = {f2bf(v0.x), f2bf(v0.y), f2bf(v0.z), f2bf(v0.w),
                            f2bf(v1.x), f2bf(v1.y), f2bf(v1.z), f2bf(v1.w)};
            *(uint4*)((char*)As + s_ldsoff) = *(const uint4*)us;
        }
        __syncthreads();
        {
            bf16x8 af0 = *(const bf16x8*)((const char*)As + abase0);
            bf16x8 af1 = *(const bf16x8*)((const char*)As + abase1);
            bf16x8 bfr[NF];
#pragma unroll
            for (int j = 0; j < NF; ++j)
                bfr[j] = *(const bf16x8*)((const char*)Bs + (wc * 4 + j) * 2048 + base[0]);
#pragma unroll
            for (int j = 0; j < NF; ++j)
                acc[j] = __builtin_amdgcn_mfma_f32_16x16x32_bf16(
                    af0, bfr[j], acc[j], 0, 0, 0);
#pragma unroll
            for (int j = 0; j < NF; ++j)
                bfr[j] = *(const bf16x8*)((const char*)Bs + (wc * 4 + j) * 2048 + base[1]);
#pragma unroll
            for (int j = 0; j < NF; ++j)
                acc[j] = __builtin_amdgcn_mfma_f32_16x16x32_bf16(
                    af1, bfr[j], acc[j], 0, 0, 0);
        }
        __syncthreads();
    }

    const int head = h0 + wc;
    float a1v[NF], a2v[NF];
#pragma unroll
    for (int cb = 0; cb < NF; ++cb) {
        int col = n0 + wc * 64 + cb * 16 + lr;
        a1v[cb] = a1[col];
        a2v[cb] = a2[col];
    }
    const int rowb = m0 + wr * 16 + lg * 4;
#pragma unroll
    for (int r = 0; r < 4; ++r) {
        int row = rowb + r;
        bool ok = row < M;
        float p1 = 0.f, p2 = 0.f;
#pragma unroll
        for (int cb = 0; cb < NF; ++cb) {
            float v = acc[cb][r];
            p1 += v * a1v[cb];
            p2 += v * a2v[cb];
            if (ok) C[(size_t)row * Ntot + n0 + wc * 64 + cb * 16 + lr] = f2bf(v);
        }
#pragma unroll
        for (int m = 1; m < 16; m <<= 1) {
            p1 += __shfl_xor(p1, m, 64);
            p2 += __shfl_xor(p2, m, 64);
        }
        if (lr == 0 && ok) {
            f1o[(size_t)row * FS + head] = p1 + b1[head];
            f2o[(size_t)row * FS + head] = p2 + b2[head];
        }
    }
}

// --------------------------- bf16 MFMA GEMM TN with fused f1/f2 epilogue
template<int BN, int K, int FS>
__global__ __launch_bounds__(256) void gemm_bf16(const ushort* __restrict__ A,
                                                 const ushort* __restrict__ B,
                                                 ushort* __restrict__ C,
                                                 int M, int Ntot,
                                                 const float* __restrict__ a1,
                                                 const float* __restrict__ b1,
                                                 const float* __restrict__ a2,
                                                 const float* __restrict__ b2,
                                                 float* __restrict__ f1o,
                                                 float* __restrict__ f2o) {
    constexpr int NF = BN / 16;
    constexpr int HH = BN / 64;
    __shared__ ushort As[64 * 64];
    __shared__ ushort Bs[BN * 64];
    const int tid = threadIdx.x;
    const int wave = tid >> 6;
    const int lane = tid & 63;
    const int lr = lane & 15;
    const int lg = lane >> 4;
    const int m0 = blockIdx.x * 64;

    int base[2];
#pragma unroll
    for (int ks = 0; ks < 2; ++ks)
        base[ks] = lr * 128 + (((ks * 4 + lg) ^ (lr & 7)) * 16);
    const int abase0 = wave * 2048 + base[0];
    const int abase1 = wave * 2048 + base[1];

    f32x4 acc[NF];
#pragma unroll
    for (int cb = 0; cb < NF; ++cb) acc[cb] = (f32x4)0.0f;

    for (int k0 = 0; k0 < K; k0 += 64) {
#pragma unroll
        for (int r = 0; r < 2; ++r) {
            int off = r * 4096 + tid * 16;
            int row = off >> 7;
            int kch = ((off >> 4) & 7) ^ (row & 7);
            const ushort* g = A + (size_t)(m0 + row) * K + k0 + kch * 8;
            __builtin_amdgcn_global_load_lds((gas_void*)g,
                                             (las_void*)((char*)As + off), 16, 0, 0);
        }
#pragma unroll
        for (int r = 0; r < BN / 32; ++r) {
            int off = r * 4096 + tid * 16;
            int row = off >> 7;
            int kch = ((off >> 4) & 7) ^ (row & 7);
            const ushort* g = B + (size_t)row * K + k0 + kch * 8;
            __builtin_amdgcn_global_load_lds((gas_void*)g,
                                             (las_void*)((char*)Bs + off), 16, 0, 0);
        }
        __syncthreads();
        {
            bf16x8 af0 = *(const bf16x8*)((const char*)As + abase0);
            bf16x8 af1 = *(const bf16x8*)((const char*)As + abase1);
#pragma unroll
            for (int cg = 0; cg < NF / 4; ++cg) {
                bf16x8 bfr[4];
#pragma unroll
                for (int j = 0; j < 4; ++j)
                    bfr[j] = *(const bf16x8*)((const char*)Bs + (cg * 4 + j) * 2048 + base[0]);
#pragma unroll
                for (int j = 0; j < 4; ++j)
                    acc[cg * 4 + j] = __builtin_amdgcn_mfma_f32_16x16x32_bf16(
                        af0, bfr[j], acc[cg * 4 + j], 0, 0, 0);
#pragma unroll
                for (int j = 0; j < 4; ++j)
                    bfr[j] = *(const bf16x8*)((const char*)Bs + (cg * 4 + j) * 2048 + base[1]);
#pragma unroll
                for (int j = 0; j < 4; ++j)
                    acc[cg * 4 + j] = __builtin_amdgcn_mfma_f32_16x16x32_bf16(
                        af1, bfr[j], acc[cg * 4 + j], 0, 0, 0);
            }
        }
        __syncthreads();
    }

    float a1v[NF], a2v[NF];
#pragma unroll
    for (int cb = 0; cb < NF; ++cb) {
        int col = cb * 16 + lr;
        a1v[cb] = a1[col];
        a2v[cb] = a2[col];
    }
    const int rowb = m0 + wave * 16 + lg * 4;
#pragma unroll
    for (int r = 0; r < 4; ++r) {
        int row = rowb + r;
        bool ok = row < M;
#pragma unroll
        for (int hh = 0; hh < HH; ++hh) {
            float p1 = 0.f, p2 = 0.f;
#pragma unroll
            for (int c4 = 0; c4 < 4; ++c4) {
                int cb = hh * 4 + c4;
                float v = acc[cb][r];
                p1 += v * a1v[cb];
                p2 += v * a2v[cb];
                if (ok) C[(size_t)row * Ntot + cb * 16 + lr] = f2bf(v);
            }
#pragma unroll
            for (int m = 1; m < 16; m <<= 1) {
                p1 += __shfl_xor(p1, m, 64);
                p2 += __shfl_xor(p2, m, 64);
            }
            if (lr == 0 && ok) {
                f1o[(size_t)row * FS + hh] = p1 + b1[hh];
                f2o[(size_t)row * FS + hh] = p2 + b2[hh];
            }
        }
    }
}

// ------------------------------------------------------------ CSR: histogram
__global__ __launch_bounds__(256) void hist_kernel(const int* __restrict__ src,
                                                   int* __restrict__ counts, int E) {
    int e = blockIdx.x * 256 + threadIdx.x;
    if (e < E) atomicAdd(&counts[src[e]], 1);
}

// ----------------------------------------- scan stage 1: per-block excl scan
__global__ __launch_bounds__(256) void scan_blk(const int* __restrict__ counts,
                                                int* __restrict__ lexcl,
                                                int* __restrict__ part, int N) {
    __shared__ int wsum[4];
    int t = threadIdx.x;
    int g = blockIdx.x * 256 + t;
    int lane = t & 63, wid = t >> 6;
    int v = (g < N) ? counts[g] : 0;
    int x = v;
#pragma unroll
    for (int off = 1; off < 64; off <<= 1) {
        int u = __shfl_up(x, off, 64);
        if (lane >= off) x += u;
    }
    if (lane == 63) wsum[wid] = x;
    __syncthreads();
    int woff = 0;
#pragma unroll
    for (int w = 0; w < 3; ++w) if (w < wid) woff += wsum[w];
    int incl = x + woff;
    if (g < N) lexcl[g] = incl - v;
    if (t == 255) part[blockIdx.x] = incl;
}

// --------------------------------- scan stage 2: excl scan of block partials
__global__ __launch_bounds__(256) void scan_part(int* __restrict__ part, int nb) {
    __shared__ int wsum[4];
    int t = threadIdx.x;
    int lane = t & 63, wid = t >> 6;
    int v = (t < nb) ? part[t] : 0;
    int x = v;
#pragma unroll
    for (int off = 1; off < 64; off <<= 1) {
        int u = __shfl_up(x, off, 64);
        if (lane >= off) x += u;
    }
    if (lane == 63) wsum[wid] = x;
    __syncthreads();
    int woff = 0;
#pragma unroll
    for (int w = 0; w < 3; ++w) if (w < wid) woff += wsum[w];
    int incl = x + woff;
    __syncthreads();
    if (t < nb) part[t] = incl - v;
    if (t == 255) part[nb] = incl;   // grand total
}

// ------------------------------------- scan stage 3: add offsets, emit CSR ptrs
__global__ __launch_bounds__(256) void scan_add(const int* __restrict__ lexcl,
                                                const int* __restrict__ part,
                                                int* __restrict__ starts,
                                                int* __restrict__ cursor, int N, int nb) {
    int g = blockIdx.x * 256 + threadIdx.x;
    if (g < N) {
        int s = lexcl[g] + part[blockIdx.x];
        starts[g] = s;
        cursor[g] = s;
    }
    if (g == 0) starts[N] = part[nb];
}

// ------------------------- CSR: position scatter (writes sorted dst directly)
__global__ __launch_bounds__(256) void scatter_kernel(const int* __restrict__ src,
                                                      const int* __restrict__ dst,
                                                      int* __restrict__ cursor,
                                                      int* __restrict__ dsts, int E) {
    int e = blockIdx.x * 256 + threadIdx.x;
    if (e >= E) return;
    int p = atomicAdd(&cursor[src[e]], 1);
    dsts[p] = dst[e];
}

// -------------- gather1, FEATURE-SLICED: slice = blockIdx&7 -> XCD-resident
// 8 slices x 32 features. Slice s's S1 column-slice (3.2MB) stays in XCD s's
// L2. 16 lanes/edge (ushort2 = 2 feats), 4 edges/pass, inline coef
// (head = slice>>1 is slice-uniform). Writes its 64B HCAT column-slice.
__global__ __launch_bounds__(256) void gather1s_kernel(const int* __restrict__ starts,
                                                       const int* __restrict__ dsts,
                                                       const float* __restrict__ f1,
                                                       const float* __restrict__ f2,
                                                       const ushort* __restrict__ S1,
                                                       const float* __restrict__ bias,
                                                       ushort* __restrict__ hcat, int N) {
    const int b = blockIdx.x;
    const int slice = b & 7;
    const int j = b >> 3;
    const int widx = threadIdx.x >> 6;
    const int lane = threadIdx.x & 63;
    const int es = lane >> 4;        // edge slot 0..3
    const int fl = lane & 15;        // feature pair: feats slice*32 + fl*2
    const int head = slice >> 1;
    const int fofs = slice * 32 + fl * 2;
    const int WPS = (int)(gridDim.x >> 3) * 4;   // waves per slice
    const int wslot = j * 4 + widx;

    const float2 bia = *(const float2*)(bias + fofs);

    int n = wslot;
    if (n >= N) return;
    int beg = starts[n];
    int end = starts[n + 1];
    for (; n < N; ) {
        int nn = n + WPS;
        int nbeg = 0, nend = 0;
        if (nn < N) {                 // prefetch next node's range
            nbeg = starts[nn];
            nend = starts[nn + 1];
        }
        float f1h = f1[(size_t)n * 4 + head];
        float a0 = 0.f, a1 = 0.f, den = 0.f;
        int i = beg;
        for (; i + 4 <= end; i += 4) {
            int d = dsts[i + es];
            float g = f2[(size_t)d * 4 + head];
            uint r = *(const uint*)(S1 + (size_t)d * HF + fofs);
            float l = f1h + g; l = l > 0.f ? l : 0.2f * l;
            float c = __expf(l);
            a0 += c * u2f(r << 16);
            a1 += c * u2f(r & 0xffff0000u);
            den += c;
        }
        if (i + es < end) {           // remainder 0..3 edges
            int d = dsts[i + es];
            float g = f2[(size_t)d * 4 + head];
            uint r = *(const uint*)(S1 + (size_t)d * HF + fofs);
            float l = f1h + g; l = l > 0.f ? l : 0.2f * l;
            float c = __expf(l);
            a0 += c * u2f(r << 16);
            a1 += c * u2f(r & 0xffff0000u);
            den += c;
        }
        // combine the 4 edge slots
        a0 += __shfl_xor(a0, 16, 64);  a0 += __shfl_xor(a0, 32, 64);
        a1 += __shfl_xor(a1, 16, 64);  a1 += __shfl_xor(a1, 32, 64);
        den += __shfl_xor(den, 16, 64); den += __shfl_xor(den, 32, 64);
        if (es == 0) {
            float rd = __builtin_amdgcn_rcpf(den);
            float v0 = a0 * rd + bia.x;
            float v1 = a1 * rd + bia.y;
            v0 = v0 > 0.f ? v0 : __expf(v0) - 1.f;
            v1 = v1 > 0.f ? v1 : __expf(v1) - 1.f;
            ushort2 o;
            o.x = f2bf(v0); o.y = f2bf(v1);
            *(ushort2*)(hcat + (size_t)n * HF + fofs) = o;
        }
        n = nn; beg = nbeg; end = nend;
    }
}

// --------------------------- gather + normalize + bias, classifier (wave/node)
// 2 edges per pass: half-wave per edge; lane owns 2 features (fl*2, fl*2+1).
__global__ __launch_bounds__(256) void gather2_kernel(const int* __restrict__ starts,
                                                      const int* __restrict__ dsts,
                                                      const float* __restrict__ f1,
                                                      const float* __restrict__ f2,
                                                      const ushort* __restrict__ S2,
                                                      const float* __restrict__ bias,
                                                      float* __restrict__ out, int N) {
    int n = (int)((blockIdx.x * blockDim.x + threadIdx.x) >> 6);
    int lane = threadIdx.x & 63;
    if (n >= N) return;
    const int es = lane >> 5;
    const int fl = lane & 31;
    const float f1u = f1[n];
    int beg = starts[n], end = starts[n + 1];
    float a0 = 0.f, a1 = 0.f, den = 0.f;
    int i = beg;

#define G2_EDGE(D)                                                            \
    {                                                                         \
        float g_ = f2[(D)];                                                   \
        uint r_ = *(const uint*)(S2 + (size_t)(D) * OUT_DIM + fl * 2);        \
        float l_ = f1u + g_; l_ = l_ > 0.f ? l_ : 0.2f * l_;                  \
        float c_ = __expf(l_);                                                \
        a0 += c_ * u2f(r_ << 16);                                             \
        a1 += c_ * u2f(r_ & 0xffff0000u);                                     \
        den += c_;                                                            \
    }

    for (; i + 4 <= end; i += 4) {
        int dA = dsts[i + es];
        int dB = dsts[i + 2 + es];
        G2_EDGE(dA);
        G2_EDGE(dB);
    }
    if (i + 2 <= end) {
        int d = dsts[i + es];
        G2_EDGE(d);
        i += 2;
    }
    if (i < end && es == 0) {
        int d = dsts[i];
        G2_EDGE(d);
    }
#undef G2_EDGE

    a0 += __shfl_xor(a0, 32, 64);
    a1 += __shfl_xor(a1, 32, 64);
    den += __shfl_xor(den, 32, 64);

    if (es == 0) {
        float rd = __builtin_amdgcn_rcpf(den);
        float2 b = *(const float2*)(bias + fl * 2);
        float2 o;
        o.x = a0 * rd + b.x;
        o.y = a1 * rd + b.y;
        *(float2*)(out + (size_t)n * OUT_DIM + fl * 2) = o;
    }
}

// ===========================================================================
extern "C" void kernel_launch(void* const* d_in, const int* in_sizes, int n_in,
                              void* d_out, int out_size, void* d_ws, size_t ws_size,
                              hipStream_t stream) {
    const float* x      = (const float*)d_in[0];
    const int*   edges  = (const int*)d_in[1];
    const float* Wlin_h = (const float*)d_in[2];
    const float* Wseq_h = (const float*)d_in[3];
    const float* a1_h   = (const float*)d_in[4];
    const float* b1_h   = (const float*)d_in[5];
    const float* a2_h   = (const float*)d_in[6];
    const float* b2_h   = (const float*)d_in[7];
    const float* bias_h = (const float*)d_in[8];
    const float* Wlin_c = (const float*)d_in[9];
    const float* Wseq_c = (const float*)d_in[10];
    const float* a1_c   = (const float*)d_in[11];
    const float* b1_c   = (const float*)d_in[12];
    const float* a2_c   = (const float*)d_in[13];
    const float* b2_c   = (const float*)d_in[14];
    const float* bias_c = (const float*)d_in[15];

    const int N = in_sizes[0] / IN_DIM;
    const int E = in_sizes[1] / 2;
    const int* src = edges;
    const int* dst = edges + E;

    char* ws = (char*)d_ws;
    size_t off = 0;
    ushort* WC1   = (ushort*)(ws + off); off += (size_t)HF * IN_DIM * 2;
    ushort* WC2   = (ushort*)(ws + off); off += (size_t)OUT_DIM * HF * 2;
    ushort* S1    = (ushort*)(ws + off); off += (size_t)N * HF * 2;
    ushort* S2    = S1;  // S1 dead after gather1; reuse for S2 [N][64]
    ushort* HCAT  = (ushort*)(ws + off); off += (size_t)N * HF * 2;
    float*  F1    = (float*)(ws + off);  off += (size_t)N * H_NUM * 4;
    float*  F2    = (float*)(ws + off);  off += (size_t)N * H_NUM * 4;
    float*  F1c   = (float*)(ws + off);  off += (size_t)N * 4;
    float*  F2c   = (float*)(ws + off);  off += (size_t)N * 4;
    int* COUNTS   = (int*)(ws + off);    off += (size_t)N * 4;
    int* STARTS   = (int*)(ws + off);    off += ((size_t)N + 1) * 4;
    int* CURSOR   = (int*)(ws + off);    off += (size_t)N * 4;
    int* DSTS     = (int*)(ws + off);    off += (size_t)E * 4;
    int* LEXCL    = (int*)(ws + off);    off += (size_t)N * 4;
    int* PART     = (int*)(ws + off);    off += 512 * 4;

    float* out = (float*)d_out;

    const int eg = (E + 255) / 256;
    const int NB = (N + 255) / 256;

    // ---- CSR build (shared by both layers); DSTS = dst sorted by src
    hipLaunchKernelGGL(zero_i32, dim3(NB), dim3(256), 0, stream, COUNTS, N);
    hipLaunchKernelGGL(hist_kernel, dim3(eg), dim3(256), 0, stream, src, COUNTS, E);
    hipLaunchKernelGGL(scan_blk, dim3(NB), dim3(256), 0, stream, COUNTS, LEXCL, PART, N);
    hipLaunchKernelGGL(scan_part, dim3(1), dim3(256), 0, stream, PART, NB);
    hipLaunchKernelGGL(scan_add, dim3(NB), dim3(256), 0, stream, LEXCL, PART, STARTS, CURSOR, N, NB);
    hipLaunchKernelGGL(scatter_kernel, dim3(eg), dim3(256), 0, stream, src, dst, CURSOR, DSTS, E);

    // ---- fold weights, both layers (bf16 out)
    hipLaunchKernelGGL(wcomb_kernel,
                       dim3((H_NUM * F_DIM * IN_DIM + OUT_DIM * HF + 255) / 256), dim3(256),
                       0, stream, Wlin_h, Wseq_h, Wlin_c, Wseq_c, WC1, WC2);

    // ---- layer 1: S1 = x @ Wc1^T  (BM=32, XCD-paired swizzle; fused f1/f2)
    {
        int nbx = (N + 31) / 32;
        int gx = 16 * ((nbx + 7) / 8);
        hipLaunchKernelGGL((gemm_f32a<128, IN_DIM, 4>), dim3(gx), dim3(256),
                           0, stream, x, WC1, S1, N, HF,
                           a1_h, b1_h, a2_h, b2_h, F1, F2);
    }

    // ---- gather layer 1, feature-sliced (slice = blockIdx&7 -> XCD-local L2)
    hipLaunchKernelGGL(gather1s_kernel, dim3(1024), dim3(256), 0, stream,
                       STARTS, DSTS, F1, F2, S1, bias_h, HCAT, N);

    // ---- classifier: S2 = hcat @ Wc2^T  (BM=64; fused f1c/f2c)
    hipLaunchKernelGGL((gemm_bf16<OUT_DIM, HF, 1>), dim3((N + 63) / 64, 1), dim3(256),
                       0, stream, HCAT, WC2, S2, N, OUT_DIM,
                       a1_c, b1_c, a2_c, b2_c, F1c, F2c);

    // ---- gather classifier (inline coef + normalize + bias) -> out fp32
    hipLaunchKernelGGL(gather2_kernel, dim3((N + 3) / 4), dim3(256), 0, stream,
                       STARTS, DSTS, F1c, F2c, S2, bias_c, out, N);
}

// Round 14
// 243.362 us; speedup vs baseline: 2.0242x; 2.0242x over previous
//
#include <hip/hip_runtime.h>
#include <hip/hip_bf16.h>
#include <cstddef>
#include <cstdint>

#define IN_DIM 512
#define R_DIM 128
#define F_DIM 64
#define H_NUM 4
#define OUT_DIM 64
#define HF 256  // H_NUM * F_DIM

typedef __attribute__((ext_vector_type(4))) float f32x4;
typedef __attribute__((ext_vector_type(8))) short bf16x8;

typedef const __attribute__((address_space(1))) void gas_void;
typedef __attribute__((address_space(3))) void las_void;

__device__ __forceinline__ float bf2f(ushort u) {
    union { uint i; float f; } v; v.i = ((uint)u) << 16; return v.f;
}
__device__ __forceinline__ ushort f2bf(float f) {
    union { float f; uint i; } v; v.f = f;
    uint r = v.i + 0x7fff + ((v.i >> 16) & 1);
    return (ushort)(r >> 16);
}
__device__ __forceinline__ float u2f(uint u) {
    union { uint i; float f; } v; v.i = u; return v.f;
}

// --------------------------- fold W_seq @ W_lin, both layers in one launch
__global__ __launch_bounds__(256) void wcomb_kernel(const float* __restrict__ WlinH,
                                                    const float* __restrict__ WseqH,
                                                    const float* __restrict__ WlinC,
                                                    const float* __restrict__ WseqC,
                                                    ushort* __restrict__ Wc1,
                                                    ushort* __restrict__ Wc2) {
    int idx = blockIdx.x * 256 + threadIdx.x;
    if (idx < H_NUM * F_DIM * IN_DIM) {
        int i  = idx & (IN_DIM - 1);
        int hf = idx >> 9;          // h*64 + f
        int h  = hf >> 6;
        const float* ws = WseqH + (size_t)hf * R_DIM;
        const float* wl = WlinH + (size_t)h * R_DIM * IN_DIM + i;
        float acc = 0.0f;
#pragma unroll 8
        for (int r = 0; r < R_DIM; ++r) acc += ws[r] * wl[(size_t)r * IN_DIM];
        Wc1[idx] = f2bf(acc);
    } else {
        int idx2 = idx - H_NUM * F_DIM * IN_DIM;
        if (idx2 >= OUT_DIM * HF) return;
        int j = idx2 & (HF - 1);
        int o = idx2 >> 8;
        const float* ws = WseqC + (size_t)o * R_DIM;
        const float* wl = WlinC + j;
        float acc = 0.0f;
#pragma unroll 8
        for (int r = 0; r < R_DIM; ++r) acc += ws[r] * wl[(size_t)r * HF];
        Wc2[idx2] = f2bf(acc);
    }
}

// ----------------------------- bf16 MFMA GEMM TN, fp32 A converted in-flight
// BM=32, BN=128, BK=64, 256 threads. LDS 20KB -> 8 blocks/CU.
template<int BN, int K, int FS>
__global__ __launch_bounds__(256) void gemm_f32a(const float* __restrict__ A,
                                                 const ushort* __restrict__ B,
                                                 ushort* __restrict__ C,
                                                 int M, int Ntot,
                                                 const float* __restrict__ a1,
                                                 const float* __restrict__ b1,
                                                 const float* __restrict__ a2,
                                                 const float* __restrict__ b2,
                                                 float* __restrict__ f1o,
                                                 float* __restrict__ f2o) {
    constexpr int NF = 4;            // 4 col-blocks (one head) per wave
    __shared__ ushort As[32 * 64];
    __shared__ ushort Bs[BN * 64];
    const int tid = threadIdx.x;
    const int wave = tid >> 6;
    const int lane = tid & 63;
    const int lr = lane & 15;
    const int lg = lane >> 4;
    const int wr = wave & 1;         // row half
    const int wc = wave >> 1;        // col half (= head within block)

    const int b = blockIdx.x;
    const int by = (b >> 3) & 1;
    const int bx = (b >> 4) * 8 + (b & 7);
    const int nbx = (M + 31) >> 5;
    if (bx >= nbx) return;
    const int m0 = bx * 32;
    const int n0 = by * BN;
    const int h0 = by * 2;

    int base[2];
#pragma unroll
    for (int ks = 0; ks < 2; ++ks)
        base[ks] = lr * 128 + (((ks * 4 + lg) ^ (lr & 7)) * 16);
    const int abase0 = wr * 2048 + base[0];
    const int abase1 = wr * 2048 + base[1];

    const int s_row = tid >> 3;
    const int s_lchunk = tid & 7;
    int s_grow = m0 + s_row;
    if (s_grow >= M) s_grow = M - 1;
    const int s_ldsoff = s_row * 128 + ((s_lchunk ^ (s_row & 7)) * 16);
    const int s_goff = s_lchunk * 8;

    f32x4 acc[NF];
#pragma unroll
    for (int cb = 0; cb < NF; ++cb) acc[cb] = (f32x4)0.0f;

    for (int k0 = 0; k0 < K; k0 += 64) {
#pragma unroll
        for (int r = 0; r < BN / 32; ++r) {
            int off = r * 4096 + tid * 16;
            int row = off >> 7;
            int kch = ((off >> 4) & 7) ^ (row & 7);
            const ushort* g = B + (size_t)(n0 + row) * K + k0 + kch * 8;
            __builtin_amdgcn_global_load_lds((gas_void*)g,
                                             (las_void*)((char*)Bs + off), 16, 0, 0);
        }
        {
            const float* g = A + (size_t)s_grow * K + k0 + s_goff;
            float4 v0 = *(const float4*)(g);
            float4 v1 = *(const float4*)(g + 4);
            ushort us[8] = {f2bf(v0.x), f2bf(v0.y), f2bf(v0.z), f2bf(v0.w),
                            f2bf(v1.x), f2bf(v1.y), f2bf(v1.z), f2bf(v1.w)};
            *(uint4*)((char*)As + s_ldsoff) = *(const uint4*)us;
        }
        __syncthreads();
        {
            bf16x8 af0 = *(const bf16x8*)((const char*)As + abase0);
            bf16x8 af1 = *(const bf16x8*)((const char*)As + abase1);
            bf16x8 bfr[NF];
#pragma unroll
            for (int j = 0; j < NF; ++j)
                bfr[j] = *(const bf16x8*)((const char*)Bs + (wc * 4 + j) * 2048 + base[0]);
#pragma unroll
            for (int j = 0; j < NF; ++j)
                acc[j] = __builtin_amdgcn_mfma_f32_16x16x32_bf16(
                    af0, bfr[j], acc[j], 0, 0, 0);
#pragma unroll
            for (int j = 0; j < NF; ++j)
                bfr[j] = *(const bf16x8*)((const char*)Bs + (wc * 4 + j) * 2048 + base[1]);
#pragma unroll
            for (int j = 0; j < NF; ++j)
                acc[j] = __builtin_amdgcn_mfma_f32_16x16x32_bf16(
                    af1, bfr[j], acc[j], 0, 0, 0);
        }
        __syncthreads();
    }

    const int head = h0 + wc;
    float a1v[NF], a2v[NF];
#pragma unroll
    for (int cb = 0; cb < NF; ++cb) {
        int col = n0 + wc * 64 + cb * 16 + lr;
        a1v[cb] = a1[col];
        a2v[cb] = a2[col];
    }
    const int rowb = m0 + wr * 16 + lg * 4;
#pragma unroll
    for (int r = 0; r < 4; ++r) {
        int row = rowb + r;
        bool ok = row < M;
        float p1 = 0.f, p2 = 0.f;
#pragma unroll
        for (int cb = 0; cb < NF; ++cb) {
            float v = acc[cb][r];
            p1 += v * a1v[cb];
            p2 += v * a2v[cb];
            if (ok) C[(size_t)row * Ntot + n0 + wc * 64 + cb * 16 + lr] = f2bf(v);
        }
#pragma unroll
        for (int m = 1; m < 16; m <<= 1) {
            p1 += __shfl_xor(p1, m, 64);
            p2 += __shfl_xor(p2, m, 64);
        }
        if (lr == 0 && ok) {
            f1o[(size_t)row * FS + head] = p1 + b1[head];
            f2o[(size_t)row * FS + head] = p2 + b2[head];
        }
    }
}

// --------------------------- bf16 MFMA GEMM TN with fused f1/f2 epilogue
// BM=64, single-buffer LDS (16 KB), gload_lds both operands.
template<int BN, int K, int FS>
__global__ __launch_bounds__(256) void gemm_bf16(const ushort* __restrict__ A,
                                                 const ushort* __restrict__ B,
                                                 ushort* __restrict__ C,
                                                 int M, int Ntot,
                                                 const float* __restrict__ a1,
                                                 const float* __restrict__ b1,
                                                 const float* __restrict__ a2,
                                                 const float* __restrict__ b2,
                                                 float* __restrict__ f1o,
                                                 float* __restrict__ f2o) {
    constexpr int NF = BN / 16;
    constexpr int HH = BN / 64;
    __shared__ ushort As[64 * 64];
    __shared__ ushort Bs[BN * 64];
    const int tid = threadIdx.x;
    const int wave = tid >> 6;
    const int lane = tid & 63;
    const int lr = lane & 15;
    const int lg = lane >> 4;
    const int m0 = blockIdx.x * 64;

    int base[2];
#pragma unroll
    for (int ks = 0; ks < 2; ++ks)
        base[ks] = lr * 128 + (((ks * 4 + lg) ^ (lr & 7)) * 16);
    const int abase0 = wave * 2048 + base[0];
    const int abase1 = wave * 2048 + base[1];

    f32x4 acc[NF];
#pragma unroll
    for (int cb = 0; cb < NF; ++cb) acc[cb] = (f32x4)0.0f;

    for (int k0 = 0; k0 < K; k0 += 64) {
#pragma unroll
        for (int r = 0; r < 2; ++r) {
            int off = r * 4096 + tid * 16;
            int row = off >> 7;
            int kch = ((off >> 4) & 7) ^ (row & 7);
            const ushort* g = A + (size_t)(m0 + row) * K + k0 + kch * 8;
            __builtin_amdgcn_global_load_lds((gas_void*)g,
                                             (las_void*)((char*)As + off), 16, 0, 0);
        }
#pragma unroll
        for (int r = 0; r < BN / 32; ++r) {
            int off = r * 4096 + tid * 16;
            int row = off >> 7;
            int kch = ((off >> 4) & 7) ^ (row & 7);
            const ushort* g = B + (size_t)row * K + k0 + kch * 8;
            __builtin_amdgcn_global_load_lds((gas_void*)g,
                                             (las_void*)((char*)Bs + off), 16, 0, 0);
        }
        __syncthreads();
        {
            bf16x8 af0 = *(const bf16x8*)((const char*)As + abase0);
            bf16x8 af1 = *(const bf16x8*)((const char*)As + abase1);
#pragma unroll
            for (int cg = 0; cg < NF / 4; ++cg) {
                bf16x8 bfr[4];
#pragma unroll
                for (int j = 0; j < 4; ++j)
                    bfr[j] = *(const bf16x8*)((const char*)Bs + (cg * 4 + j) * 2048 + base[0]);
#pragma unroll
                for (int j = 0; j < 4; ++j)
                    acc[cg * 4 + j] = __builtin_amdgcn_mfma_f32_16x16x32_bf16(
                        af0, bfr[j], acc[cg * 4 + j], 0, 0, 0);
#pragma unroll
                for (int j = 0; j < 4; ++j)
                    bfr[j] = *(const bf16x8*)((const char*)Bs + (cg * 4 + j) * 2048 + base[1]);
#pragma unroll
                for (int j = 0; j < 4; ++j)
                    acc[cg * 4 + j] = __builtin_amdgcn_mfma_f32_16x16x32_bf16(
                        af1, bfr[j], acc[cg * 4 + j], 0, 0, 0);
            }
        }
        __syncthreads();
    }

    float a1v[NF], a2v[NF];
#pragma unroll
    for (int cb = 0; cb < NF; ++cb) {
        int col = cb * 16 + lr;
        a1v[cb] = a1[col];
        a2v[cb] = a2[col];
    }
    const int rowb = m0 + wave * 16 + lg * 4;
#pragma unroll
    for (int r = 0; r < 4; ++r) {
        int row = rowb + r;
        bool ok = row < M;
#pragma unroll
        for (int hh = 0; hh < HH; ++hh) {
            float p1 = 0.f, p2 = 0.f;
#pragma unroll
            for (int c4 = 0; c4 < 4; ++c4) {
                int cb = hh * 4 + c4;
                float v = acc[cb][r];
                p1 += v * a1v[cb];
                p2 += v * a2v[cb];
                if (ok) C[(size_t)row * Ntot + cb * 16 + lr] = f2bf(v);
            }
#pragma unroll
            for (int m = 1; m < 16; m <<= 1) {
                p1 += __shfl_xor(p1, m, 64);
                p2 += __shfl_xor(p2, m, 64);
            }
            if (lr == 0 && ok) {
                f1o[(size_t)row * FS + hh] = p1 + b1[hh];
                f2o[(size_t)row * FS + hh] = p2 + b2[hh];
            }
        }
    }
}

// ------------------------------------------------------------ CSR: histogram
__global__ __launch_bounds__(256) void hist_kernel(const int* __restrict__ src,
                                                   int* __restrict__ counts, int E) {
    int e = blockIdx.x * 256 + threadIdx.x;
    if (e < E) atomicAdd(&counts[src[e]], 1);
}

// ----------------------------------------- scan stage 1: per-block excl scan
__global__ __launch_bounds__(256) void scan_blk(const int* __restrict__ counts,
                                                int* __restrict__ lexcl,
                                                int* __restrict__ part, int N) {
    __shared__ int wsum[4];
    int t = threadIdx.x;
    int g = blockIdx.x * 256 + t;
    int lane = t & 63, wid = t >> 6;
    int v = (g < N) ? counts[g] : 0;
    int x = v;
#pragma unroll
    for (int off = 1; off < 64; off <<= 1) {
        int u = __shfl_up(x, off, 64);
        if (lane >= off) x += u;
    }
    if (lane == 63) wsum[wid] = x;
    __syncthreads();
    int woff = 0;
#pragma unroll
    for (int w = 0; w < 3; ++w) if (w < wid) woff += wsum[w];
    int incl = x + woff;
    if (g < N) lexcl[g] = incl - v;
    if (t == 255) part[blockIdx.x] = incl;
}

// --------------------------------- scan stage 2: excl scan of block partials
__global__ __launch_bounds__(256) void scan_part(int* __restrict__ part, int nb) {
    __shared__ int wsum[4];
    int t = threadIdx.x;
    int lane = t & 63, wid = t >> 6;
    int v = (t < nb) ? part[t] : 0;
    int x = v;
#pragma unroll
    for (int off = 1; off < 64; off <<= 1) {
        int u = __shfl_up(x, off, 64);
        if (lane >= off) x += u;
    }
    if (lane == 63) wsum[wid] = x;
    __syncthreads();
    int woff = 0;
#pragma unroll
    for (int w = 0; w < 3; ++w) if (w < wid) woff += wsum[w];
    int incl = x + woff;
    __syncthreads();
    if (t < nb) part[t] = incl - v;
    if (t == 255) part[nb] = incl;   // grand total
}

// ------------------------------------- scan stage 3: add offsets, emit CSR ptrs
__global__ __launch_bounds__(256) void scan_add(const int* __restrict__ lexcl,
                                                const int* __restrict__ part,
                                                int* __restrict__ starts,
                                                int* __restrict__ cursor, int N, int nb) {
    int g = blockIdx.x * 256 + threadIdx.x;
    if (g < N) {
        int s = lexcl[g] + part[blockIdx.x];
        starts[g] = s;
        cursor[g] = s;
    }
    if (g == 0) starts[N] = part[nb];
}

// ------------------------- CSR: position scatter (writes sorted dst directly)
__global__ __launch_bounds__(256) void scatter_kernel(const int* __restrict__ src,
                                                      const int* __restrict__ dst,
                                                      int* __restrict__ cursor,
                                                      int* __restrict__ dsts, int E) {
    int e = blockIdx.x * 256 + threadIdx.x;
    if (e >= E) return;
    int p = atomicAdd(&cursor[src[e]], 1);
    dsts[p] = dst[e];
}

// ----------------------- gather + normalize + bias + ELU, heads (wave/node)
// 2 edges per pass: half-wave es handles edge i+es; lane owns 8 features
// (fl*8..+7, head = fl>>3) -> one uint4 (16B) row load per edge -> 1KB/instr.
__global__ __launch_bounds__(256) void gather1_kernel(const int* __restrict__ starts,
                                                      const int* __restrict__ dsts,
                                                      const float* __restrict__ f1,
                                                      const float* __restrict__ f2,
                                                      const ushort* __restrict__ S1,
                                                      const float* __restrict__ bias,
                                                      ushort* __restrict__ hcat, int N) {
    int n = (int)((blockIdx.x * blockDim.x + threadIdx.x) >> 6);
    int lane = threadIdx.x & 63;
    if (n >= N) return;
    const int es = lane >> 5;      // edge slot 0/1
    const int fl = lane & 31;      // feature lane: feats fl*8..fl*8+7
    const int head = fl >> 3;
    const float f1h = f1[(size_t)n * 4 + head];
    int beg = starts[n], end = starts[n + 1];
    float a[8] = {};
    float den = 0.f;
    int i = beg;

#define G1_EDGE(D)                                                            \
    {                                                                         \
        float g_ = f2[(size_t)(D) * 4 + head];                                \
        uint4 r_ = *(const uint4*)(S1 + (size_t)(D) * HF + fl * 8);           \
        float l_ = f1h + g_; l_ = l_ > 0.f ? l_ : 0.2f * l_;                  \
        float c_ = __expf(l_);                                                \
        a[0] += c_ * u2f(r_.x << 16);  a[1] += c_ * u2f(r_.x & 0xffff0000u);  \
        a[2] += c_ * u2f(r_.y << 16);  a[3] += c_ * u2f(r_.y & 0xffff0000u);  \
        a[4] += c_ * u2f(r_.z << 16);  a[5] += c_ * u2f(r_.z & 0xffff0000u);  \
        a[6] += c_ * u2f(r_.w << 16);  a[7] += c_ * u2f(r_.w & 0xffff0000u);  \
        den += c_;                                                            \
    }

    for (; i + 4 <= end; i += 4) {       // 4 edges: 2 passes in flight
        int dA = dsts[i + es];
        int dB = dsts[i + 2 + es];
        G1_EDGE(dA);
        G1_EDGE(dB);
    }
    if (i + 2 <= end) {                  // one 2-edge pass
        int d = dsts[i + es];
        G1_EDGE(d);
        i += 2;
    }
    if (i < end && es == 0) {            // final single edge, half-wave
        int d = dsts[i];
        G1_EDGE(d);
    }
#undef G1_EDGE

    // combine the two edge-slots
#pragma unroll
    for (int k = 0; k < 8; ++k) a[k] += __shfl_xor(a[k], 32, 64);
    den += __shfl_xor(den, 32, 64);

    if (es == 0) {
        float rd = __builtin_amdgcn_rcpf(den);
        float4 b0 = *(const float4*)(bias + fl * 8);
        float4 b1 = *(const float4*)(bias + fl * 8 + 4);
        float v[8];
        v[0] = a[0] * rd + b0.x; v[1] = a[1] * rd + b0.y;
        v[2] = a[2] * rd + b0.z; v[3] = a[3] * rd + b0.w;
        v[4] = a[4] * rd + b1.x; v[5] = a[5] * rd + b1.y;
        v[6] = a[6] * rd + b1.z; v[7] = a[7] * rd + b1.w;
        ushort us[8];
#pragma unroll
        for (int k = 0; k < 8; ++k) {
            float vv = v[k] > 0.f ? v[k] : __expf(v[k]) - 1.f;
            us[k] = f2bf(vv);
        }
        *(uint4*)(hcat + (size_t)n * HF + fl * 8) = *(const uint4*)us;
    }
}

// --------------------------- gather + normalize + bias, classifier (wave/node)
// 2 edges per pass: half-wave per edge; lane owns 2 features (fl*2, fl*2+1).
__global__ __launch_bounds__(256) void gather2_kernel(const int* __restrict__ starts,
                                                      const int* __restrict__ dsts,
                                                      const float* __restrict__ f1,
                                                      const float* __restrict__ f2,
                                                      const ushort* __restrict__ S2,
                                                      const float* __restrict__ bias,
                                                      float* __restrict__ out, int N) {
    int n = (int)((blockIdx.x * blockDim.x + threadIdx.x) >> 6);
    int lane = threadIdx.x & 63;
    if (n >= N) return;
    const int es = lane >> 5;
    const int fl = lane & 31;
    const float f1u = f1[n];
    int beg = starts[n], end = starts[n + 1];
    float a0 = 0.f, a1 = 0.f, den = 0.f;
    int i = beg;

#define G2_EDGE(D)                                                            \
    {                                                                         \
        float g_ = f2[(D)];                                                   \
        uint r_ = *(const uint*)(S2 + (size_t)(D) * OUT_DIM + fl * 2);        \
        float l_ = f1u + g_; l_ = l_ > 0.f ? l_ : 0.2f * l_;                  \
        float c_ = __expf(l_);                                                \
        a0 += c_ * u2f(r_ << 16);                                             \
        a1 += c_ * u2f(r_ & 0xffff0000u);                                     \
        den += c_;                                                            \
    }

    for (; i + 4 <= end; i += 4) {
        int dA = dsts[i + es];
        int dB = dsts[i + 2 + es];
        G2_EDGE(dA);
        G2_EDGE(dB);
    }
    if (i + 2 <= end) {
        int d = dsts[i + es];
        G2_EDGE(d);
        i += 2;
    }
    if (i < end && es == 0) {
        int d = dsts[i];
        G2_EDGE(d);
    }
#undef G2_EDGE

    a0 += __shfl_xor(a0, 32, 64);
    a1 += __shfl_xor(a1, 32, 64);
    den += __shfl_xor(den, 32, 64);

    if (es == 0) {
        float rd = __builtin_amdgcn_rcpf(den);
        float2 b = *(const float2*)(bias + fl * 2);
        float2 o;
        o.x = a0 * rd + b.x;
        o.y = a1 * rd + b.y;
        *(float2*)(out + (size_t)n * OUT_DIM + fl * 2) = o;
    }
}

// ===========================================================================
extern "C" void kernel_launch(void* const* d_in, const int* in_sizes, int n_in,
                              void* d_out, int out_size, void* d_ws, size_t ws_size,
                              hipStream_t stream) {
    const float* x      = (const float*)d_in[0];
    const int*   edges  = (const int*)d_in[1];
    const float* Wlin_h = (const float*)d_in[2];
    const float* Wseq_h = (const float*)d_in[3];
    const float* a1_h   = (const float*)d_in[4];
    const float* b1_h   = (const float*)d_in[5];
    const float* a2_h   = (const float*)d_in[6];
    const float* b2_h   = (const float*)d_in[7];
    const float* bias_h = (const float*)d_in[8];
    const float* Wlin_c = (const float*)d_in[9];
    const float* Wseq_c = (const float*)d_in[10];
    const float* a1_c   = (const float*)d_in[11];
    const float* b1_c   = (const float*)d_in[12];
    const float* a2_c   = (const float*)d_in[13];
    const float* b2_c   = (const float*)d_in[14];
    const float* bias_c = (const float*)d_in[15];

    const int N = in_sizes[0] / IN_DIM;
    const int E = in_sizes[1] / 2;
    const int* src = edges;
    const int* dst = edges + E;

    char* ws = (char*)d_ws;
    size_t off = 0;
    ushort* WC1   = (ushort*)(ws + off); off += (size_t)HF * IN_DIM * 2;
    ushort* WC2   = (ushort*)(ws + off); off += (size_t)OUT_DIM * HF * 2;
    ushort* S1    = (ushort*)(ws + off); off += (size_t)N * HF * 2;
    ushort* S2    = S1;  // S1 dead after gather1; reuse for S2 [N][64]
    ushort* HCAT  = (ushort*)(ws + off); off += (size_t)N * HF * 2;
    float*  F1    = (float*)(ws + off);  off += (size_t)N * H_NUM * 4;
    float*  F2    = (float*)(ws + off);  off += (size_t)N * H_NUM * 4;
    float*  F1c   = (float*)(ws + off);  off += (size_t)N * 4;
    float*  F2c   = (float*)(ws + off);  off += (size_t)N * 4;
    int* COUNTS   = (int*)(ws + off);    off += (size_t)N * 4;
    int* STARTS   = (int*)(ws + off);    off += ((size_t)N + 1) * 4;
    int* CURSOR   = (int*)(ws + off);    off += (size_t)N * 4;
    int* DSTS     = (int*)(ws + off);    off += (size_t)E * 4;
    int* LEXCL    = (int*)(ws + off);    off += (size_t)N * 4;
    int* PART     = (int*)(ws + off);    off += 512 * 4;

    float* out = (float*)d_out;

    const int eg = (E + 255) / 256;
    const int NB = (N + 255) / 256;

    // ---- CSR build (shared by both layers); DSTS = dst sorted by src
    hipMemsetAsync(COUNTS, 0, (size_t)N * 4, stream);
    hipLaunchKernelGGL(hist_kernel, dim3(eg), dim3(256), 0, stream, src, COUNTS, E);
    hipLaunchKernelGGL(scan_blk, dim3(NB), dim3(256), 0, stream, COUNTS, LEXCL, PART, N);
    hipLaunchKernelGGL(scan_part, dim3(1), dim3(256), 0, stream, PART, NB);
    hipLaunchKernelGGL(scan_add, dim3(NB), dim3(256), 0, stream, LEXCL, PART, STARTS, CURSOR, N, NB);
    hipLaunchKernelGGL(scatter_kernel, dim3(eg), dim3(256), 0, stream, src, dst, CURSOR, DSTS, E);

    // ---- fold weights, both layers (bf16 out)
    hipLaunchKernelGGL(wcomb_kernel,
                       dim3((H_NUM * F_DIM * IN_DIM + OUT_DIM * HF + 255) / 256), dim3(256),
                       0, stream, Wlin_h, Wseq_h, Wlin_c, Wseq_c, WC1, WC2);

    // ---- layer 1: S1 = x @ Wc1^T  (BM=32, XCD-paired swizzle; fused f1/f2)
    {
        int nbx = (N + 31) / 32;
        int gx = 16 * ((nbx + 7) / 8);
        hipLaunchKernelGGL((gemm_f32a<128, IN_DIM, 4>), dim3(gx), dim3(256),
                           0, stream, x, WC1, S1, N, HF,
                           a1_h, b1_h, a2_h, b2_h, F1, F2);
    }

    // ---- gather layer 1 (inline coef + normalize + bias + ELU) -> HCAT bf16
    hipLaunchKernelGGL(gather1_kernel, dim3((N + 3) / 4), dim3(256), 0, stream,
                       STARTS, DSTS, F1, F2, S1, bias_h, HCAT, N);

    // ---- classifier: S2 = hcat @ Wc2^T  (BM=64; fused f1c/f2c)
    hipLaunchKernelGGL((gemm_bf16<OUT_DIM, HF, 1>), dim3((N + 63) / 64, 1), dim3(256),
                       0, stream, HCAT, WC2, S2, N, OUT_DIM,
                       a1_c, b1_c, a2_c, b2_c, F1c, F2c);

    // ---- gather classifier (inline coef + normalize + bias) -> out fp32
    hipLaunchKernelGGL(gather2_kernel, dim3((N + 3) / 4), dim3(256), 0, stream,
                       STARTS, DSTS, F1c, F2c, S2, bias_c, out, N);
}